// Round 8
// baseline (43.984 us; speedup 1.0000x reference)
//
#include <hip/hip_runtime.h>
#include <hip/hip_bf16.h>
#include <stdint.h>

#define THREADS 256
#define ROWS_PER_BLOCK 8
#define JSPLIT 4
#define EMB_ROWS 5050

typedef _Float16 half2v __attribute__((ext_vector_type(2)));
typedef __fp16   fp16x2 __attribute__((ext_vector_type(2)));

__device__ __forceinline__ half2v pk(float a, float b) {
    fp16x2 r = __builtin_amdgcn_cvt_pkrtz(a, b);   // v_cvt_pkrtz_f16_f32
    return __builtin_bit_cast(half2v, r);
}
__device__ __forceinline__ half2v pkfma(half2v a, half2v b, half2v c) {
    return __builtin_elementwise_fma(a, b, c);     // v_pk_fma_f16
}

// Each block: 8 rows (i) x a 1024-wide slice of columns (j).
// emb staged in LDS as duplicated f16 pairs (e,e) -> ds_read_b32 yields the
// packed MLP input directly. Layer-1 packed f16, layer-2 v_dot2_f32_f16.
// rsqrt via raw v_rsq_f32 (__builtin_amdgcn_rsqf): rsqrtf() without
// fast-math expands to the ~25-inst IEEE sqrt+div sequence (R3-R7 flatline).
__global__ __launch_bounds__(THREADS, 4) void energy_main_kernel(
    const float* __restrict__ coords,
    const int*   __restrict__ atom_ix,
    const float* __restrict__ charges,
    const float* __restrict__ emb,
    const float* __restrict__ W1,
    const float* __restrict__ b1,
    const float* __restrict__ W2,
    const float* __restrict__ b2,
    float* __restrict__ partials,
    int n_atoms)
{
    __shared__ uint32_t s_emb2[EMB_ROWS];
    for (int t = threadIdx.x; t < EMB_ROWS; t += THREADS) {
        const float e = emb[t];
        s_emb2[t] = __builtin_bit_cast(uint32_t, pk(e, e));
    }

    // k-packed weights. A2/B2/U*_2 stay wave-uniform (SGPR); C2 is forced
    // into VGPRs so pkfma(c2[v], B2[s], C2[v]) reads only one SGPR operand.
    half2v A2[8], B2[8], U0_2[8], U1_2[8], U2_2[8];
    uint32_t C2v[8];
#pragma unroll
    for (int p = 0; p < 8; ++p) {
        A2[p]   = pk(W1[2 * p],      W1[2 * p + 1]);        // W1[0][k]
        B2[p]   = pk(W1[16 + 2 * p], W1[16 + 2 * p + 1]);   // W1[1][k]
        C2v[p]  = __builtin_bit_cast(uint32_t, pk(b1[2 * p], b1[2 * p + 1]));
        asm("" : "+v"(C2v[p]));                             // keep in VGPR
        U0_2[p] = pk(W2[3 * (2 * p) + 0], W2[3 * (2 * p + 1) + 0]);
        U1_2[p] = pk(W2[3 * (2 * p) + 1], W2[3 * (2 * p + 1) + 1]);
        U2_2[p] = pk(W2[3 * (2 * p) + 2], W2[3 * (2 * p + 1) + 2]);
    }
    const float bo0 = b2[0], bo1 = b2[1], bo2 = b2[2];

    const int rb   = blockIdx.x / JSPLIT;
    const int js   = blockIdx.x % JSPLIT;
    const int row0 = rb * ROWS_PER_BLOCK;
    const int jlen = n_atoms / JSPLIT;
    const int j0   = js * jlen;

    float  xr[ROWS_PER_BLOCK], yr[ROWS_PER_BLOCK], zr[ROWS_PER_BLOCK];
    half2v qr2[ROWS_PER_BLOCK];
    int    br[ROWS_PER_BLOCK];
#pragma unroll
    for (int r = 0; r < ROWS_PER_BLOCK; ++r) {
        const int i = row0 + r;
        xr[r] = coords[3 * i + 0];
        yr[r] = coords[3 * i + 1];
        zr[r] = coords[3 * i + 2];
        const float q = charges[i];
        qr2[r] = pk(q, q);
        const int a = atom_ix[i];
        br[r] = (a * (a + 1)) >> 1;
    }
    __syncthreads();

    float cacc = 0.0f, ljacc = 0.0f;
    const half2v zero2 = (half2v)(_Float16)0.0f;

#pragma unroll 1
    for (int j = j0 + threadIdx.x; j < j0 + jlen; j += THREADS) {
        const float xj = coords[3 * j + 0];
        const float yj = coords[3 * j + 1];
        const float zj = coords[3 * j + 2];
        const float qj = charges[j];
        const half2v qj2 = pk(qj, qj);
        const int   aj = atom_ix[j];

#pragma unroll
        for (int r = 0; r < ROWS_PER_BLOCK; ++r) {
            const float dx = xj - xr[r];
            const float dy = yj - yr[r];
            const float dz = zj - zr[r];
            const float sq = fmaf(dx, dx, fmaf(dy, dy, dz * dz));
            // sq==0 (diagonal): v_rsq_f32(0)=+inf, fminf(inf,10)=10 -> matches
            // the reference's nan_to_num + clamp-to-10 semantics exactly.
            const float rd = fminf(__builtin_amdgcn_rsqf(sq), 10.0f);

            const half2v e2 = __builtin_bit_cast(half2v, s_emb2[br[r] + aj]);
            const half2v c2 = qr2[r] * qj2;               // v_pk_mul_f16

            float o0 = bo0, o1 = bo1, o2 = bo2;
#pragma unroll
            for (int p = 0; p < 8; ++p) {
                half2v t = pkfma(c2, B2[p], __builtin_bit_cast(half2v, C2v[p]));
                t = pkfma(e2, A2[p], t);
                t = __builtin_elementwise_max(t, zero2);  // v_pk_max_f16
                o0 = __builtin_amdgcn_fdot2(t, U0_2[p], o0, false);
                o1 = __builtin_amdgcn_fdot2(t, U1_2[p], o1, false);
                o2 = __builtin_amdgcn_fdot2(t, U2_2[p], o2, false);
            }

            cacc = fmaf(o0, rd, cacc);
            const float sr  = o1 * rd;
            const float sr2 = sr * sr;
            const float sr6 = sr2 * sr2 * sr2;
            ljacc = fmaf(o2, fmaf(sr6, sr6, -sr6), ljacc);
        }
    }

    // Deterministic in-block reduction: wave shuffle, then LDS across waves.
#pragma unroll
    for (int off = 32; off > 0; off >>= 1) {
        cacc  += __shfl_down(cacc, off, 64);
        ljacc += __shfl_down(ljacc, off, 64);
    }
    __shared__ float s_c[THREADS / 64], s_l[THREADS / 64];
    const int wave = threadIdx.x >> 6;
    const int lane = threadIdx.x & 63;
    if (lane == 0) { s_c[wave] = cacc; s_l[wave] = ljacc; }
    __syncthreads();
    if (threadIdx.x == 0) {
        float ct = 0.0f, lt = 0.0f;
#pragma unroll
        for (int w = 0; w < THREADS / 64; ++w) { ct += s_c[w]; lt += s_l[w]; }
        partials[2 * blockIdx.x + 0] = ct;
        partials[2 * blockIdx.x + 1] = lt;
    }
}

// Final reduction over block partials (fixed order -> deterministic).
__global__ __launch_bounds__(THREADS, 1) void energy_reduce_kernel(
    const float* __restrict__ partials, int nblocks,
    const float* __restrict__ bias, float* __restrict__ out)
{
    float ct = 0.0f, lt = 0.0f;
    for (int b = threadIdx.x; b < nblocks; b += THREADS) {
        ct += partials[2 * b + 0];
        lt += partials[2 * b + 1];
    }
#pragma unroll
    for (int off = 32; off > 0; off >>= 1) {
        ct += __shfl_down(ct, off, 64);
        lt += __shfl_down(lt, off, 64);
    }
    __shared__ float s_c[THREADS / 64], s_l[THREADS / 64];
    const int wave = threadIdx.x >> 6;
    const int lane = threadIdx.x & 63;
    if (lane == 0) { s_c[wave] = ct; s_l[wave] = lt; }
    __syncthreads();
    if (threadIdx.x == 0) {
        float c = 0.0f, l = 0.0f;
#pragma unroll
        for (int w = 0; w < THREADS / 64; ++w) { c += s_c[w]; l += s_l[w]; }
        // COULOMB_CONSTANT = -1, EV = 1.602e-19
        out[0] = -c + 1.602e-19f * l + bias[0];
    }
}

extern "C" void kernel_launch(void* const* d_in, const int* in_sizes, int n_in,
                              void* d_out, int out_size, void* d_ws, size_t ws_size,
                              hipStream_t stream)
{
    const float* coords  = (const float*)d_in[0];
    const int*   atom_ix = (const int*)d_in[1];
    const float* charges = (const float*)d_in[2];
    const float* emb     = (const float*)d_in[3];
    const float* W1      = (const float*)d_in[4];
    const float* b1      = (const float*)d_in[5];
    const float* W2      = (const float*)d_in[6];
    const float* b2      = (const float*)d_in[7];
    const float* bias    = (const float*)d_in[8];

    float* out      = (float*)d_out;
    float* partials = (float*)d_ws;

    const int n       = in_sizes[1];                       // 4096 atoms
    const int nblocks = (n / ROWS_PER_BLOCK) * JSPLIT;     // 2048 blocks

    energy_main_kernel<<<nblocks, THREADS, 0, stream>>>(
        coords, atom_ix, charges, emb, W1, b1, W2, b2, partials, n);
    energy_reduce_kernel<<<1, THREADS, 0, stream>>>(partials, nblocks, bias, out);
}